// Round 15
// baseline (333.155 us; speedup 1.0000x reference)
//
#include <hip/hip_runtime.h>
#include <hip/hip_bf16.h>

// ---------------------------------------------------------------------------
// attention via: E = exp(QK^T/32) (bf16), inv[r] = 1/sum_k E[r,k] (per-wave
// partials), O = diag(inv)*E*V.
// r15 = r13 with GEMM1 moved to the BM=128 instantiation (the shape that
// measured 1.13 PF as GEMM2 in r12/r13, vs 0.9 PF for BM=256):
//   GEMM1: gemm8d<128,OUT=0,DEC=2>, grid 2048 (64bm x 32bn). DEC=2 decode:
//          256 wgs/XCD chunk -> 8 subchunks of 32 = 8bm x 4bn (4MB L2 ws).
//   GEMM2: unchanged gemm8d<128,OUT=1,DEC=1>, grid 256 (8bm x 4bn stripes).
// Template (verified r12/r13): 8 phases / 2 K-tiles, 2-tile-ahead staging
// into dead regions, counted WAITV(4) at ph3/ph7 only (never 0 mid-loop),
// T2 both-sides XOR swizzle (0 conflicts), T5 setprio, de-pinned sync.
// ws: [0,128MB)=E ; [128,144MB)=V^T ; [144,148MB)=partials[8192][128] ; inv.
// d_out holds bf16 Q|K scratch until GEMM2 overwrites it.
// ---------------------------------------------------------------------------

typedef __bf16 bf16x8 __attribute__((ext_vector_type(8)));
typedef float f32x4 __attribute__((ext_vector_type(4)));
typedef const __attribute__((address_space(1))) unsigned int* as1p;
typedef __attribute__((address_space(3))) unsigned int* as3p;
typedef unsigned short u16;

__device__ __forceinline__ u16 f2bf(float x) {
  unsigned u = __float_as_uint(x);
  u += 0x7fffu + ((u >> 16) & 1u);
  return (u16)(u >> 16);
}
__device__ __forceinline__ float bf2f(u16 b) { return __uint_as_float(((unsigned)b) << 16); }
__device__ __forceinline__ unsigned pack2(float lo, float hi) {
  return (unsigned)f2bf(lo) | ((unsigned)f2bf(hi) << 16);
}

#define BARX()   __builtin_amdgcn_s_barrier()
#define WAITL()  asm volatile("s_waitcnt lgkmcnt(0)")
#define WAITV(n) asm volatile("s_waitcnt vmcnt(" #n ")")

// --------------------------- f32 -> bf16 convert ---------------------------
__global__ __launch_bounds__(256) void cvt_bf16(const float* __restrict__ in,
                                                unsigned short* __restrict__ out) {
  const size_t i = (size_t)blockIdx.x * 256 + threadIdx.x;
  const float4* p = (const float4*)in + i * 2;
  float4 a = p[0], b = p[1];
  uint4 o;
  o.x = pack2(a.x, a.y);
  o.y = pack2(a.z, a.w);
  o.z = pack2(b.x, b.y);
  o.w = pack2(b.z, b.w);
  ((uint4*)out)[i] = o;
}

// ------------- V [8192,1024] f32 -> V^T [1024,8192] bf16 -------------------
__global__ __launch_bounds__(256) void transpose_bf16(const float* __restrict__ V,
                                                      unsigned short* __restrict__ VT) {
  __shared__ float t[64][65];
  const int rb = blockIdx.x * 64;
  const int cb = blockIdx.y * 64;
  const int tid = threadIdx.x;
#pragma unroll
  for (int it = 0; it < 4; ++it) {
    int r = it * 16 + (tid >> 4);
    int c = (tid & 15) * 4;
    float4 x = *(const float4*)(V + (size_t)(rb + r) * 1024 + cb + c);
    t[r][c] = x.x; t[r][c + 1] = x.y; t[r][c + 2] = x.z; t[r][c + 3] = x.w;
  }
  __syncthreads();
  const int j = tid & 63;
  const int c0 = (tid >> 6) * 16;
#pragma unroll
  for (int i = 0; i < 16; ++i) {
    int c = c0 + i;
    VT[(size_t)(cb + c) * 8192 + rb + j] = f2bf(t[j][c]);
  }
}

// -------------- 8-phase NT GEMM, 2-tile-ahead staging, de-pinned -----------
// C[M,N](ldc) = A[M,K]*B[N,K]^T, BN=256. 512 threads, 8 waves (2M x 4N).
// DEC 0: grid 1024 = supertile 16bm x 8bn per XCD chunk  [legacy BM=256]
// DEC 1: grid 256  = 8bm x 4bn per XCD chunk (bn fastest) [GEMM2]
// DEC 2: grid 2048 = 8 subchunks of (8bm x 4bn) per XCD chunk [GEMM1 BM=128]
// OUTMODE 0: C=bf16 exp(acc*scale) + per-wave row partials.
// OUTMODE 1: C=f32 acc*inv[row].
template <int BM, int OUTMODE, int DEC>
__global__ __launch_bounds__(512, 2) void gemm8d(const u16* __restrict__ A,
                                                 const u16* __restrict__ B,
                                                 void* __restrict__ Cv,
                                                 const float* __restrict__ inv,
                                                 float* __restrict__ partials,
                                                 int K, int ldc, float scale) {
  constexpr int MF = BM / 32;       // per-wave m-frags (8 or 4)
  constexpr int MH = MF / 2;        // m-frags per half
  constexpr int ABUF = BM * 128;
  constexpr int BBUF = 32768;
  constexpr int BUFSZ = ABUF + BBUF;
  __shared__ __align__(1024) char smem[2 * BUFSZ];

  const int tid = threadIdx.x;
  const int lane = tid & 63, wave = tid >> 6;
  const int wr = wave >> 2, wc = wave & 3;
  const int lan15 = lane & 15, g = lane >> 4, l7 = lane & 7;

  // T1: bijective XCD swizzle (nwg % 8 == 0 at all call sites)
  const int nwg = gridDim.x;
  const int wg = (blockIdx.x & 7) * (nwg >> 3) + (blockIdx.x >> 3);
  int bm0, bn0;
  if constexpr (DEC == 0) {
    const int r = wg & 255;
    bm0 = (r >> 3) * 256;
    bn0 = (((wg >> 8) << 3) | (r & 7)) * 256;
  } else if constexpr (DEC == 1) {
    // 256 wgs: XCD chunk of 32 = 8 bm x 4 bn, bn fastest
    const int chunk = wg >> 5;
    const int within = wg & 31;
    bm0 = (chunk * 8 + (within >> 2)) * BM;
    bn0 = (within & 3) * 256;
  } else {
    // 2048 wgs: XCD chunk of 256 = 8 subchunks x (8bm x 4bn), bn fastest.
    // Resident set per XCD at any time ~ one subchunk: A 2MB + B 2MB = L2-fit.
    const int chunk = wg >> 8;          // 0..7
    const int r8 = wg & 255;
    const int sub = r8 >> 5;            // 0..7
    const int win = r8 & 31;
    bm0 = (chunk * 8 + (win >> 2)) * BM;        // 64 bm blocks total
    bn0 = (sub * 4 + (win & 3)) * 256;          // 32 bn blocks total
  }

  // staging: thread -> row (tid>>3), swizzled src col-block (tid&7)^(row&7)
  const int sr = tid >> 3;
  const int scb = ((tid & 7) ^ (sr & 7)) * 8;
  const u16* Ags = A + (size_t)(bm0 + sr) * K + scb;
  const u16* Bgs = B + (size_t)(bn0 + sr) * K + scb;

  // fragment-read swizzled 16B-slot offsets
  const int sa0 = ((0 + g) ^ l7) * 16;
  const int sa1 = ((4 + g) ^ l7) * 16;
  const int abase = (wr * (BM / 2) + lan15) * 128;
  const int bbase = ABUF + (wc * 64 + lan15) * 128;

  f32x4 acc[MF][4];
#pragma unroll
  for (int m = 0; m < MF; ++m)
#pragma unroll
    for (int n = 0; n < 4; ++n) acc[m][n] = f32x4{0.f, 0.f, 0.f, 0.f};

  const int nt = K >> 6;
  const int niter = nt >> 1;

  // stage units: 2 x global_load_lds each, explicit j-batches (64 rows each)
  auto IA = [&](int t, int ja, int jb) {
    char* bb = smem + (t & 1) * BUFSZ;
    const size_t ko = (size_t)t * 64;
    __builtin_amdgcn_global_load_lds((as1p)(Ags + (size_t)ja * 64 * K + ko),
                                     (as3p)(bb + ja * 8192 + tid * 16), 16, 0, 0);
    __builtin_amdgcn_global_load_lds((as1p)(Ags + (size_t)jb * 64 * K + ko),
                                     (as3p)(bb + jb * 8192 + tid * 16), 16, 0, 0);
  };
  auto IB = [&](int t, int j0) {  // batches j0, j0+1
    char* bb = smem + (t & 1) * BUFSZ + ABUF;
    const size_t ko = (size_t)t * 64;
    __builtin_amdgcn_global_load_lds((as1p)(Bgs + (size_t)j0 * 64 * K + ko),
                                     (as3p)(bb + j0 * 8192 + tid * 16), 16, 0, 0);
    __builtin_amdgcn_global_load_lds((as1p)(Bgs + (size_t)(j0 + 1) * 64 * K + ko),
                                     (as3p)(bb + (j0 + 1) * 8192 + tid * 16), 16, 0, 0);
  };
  auto IA_mh0 = [&](int t) { if constexpr (BM == 256) IA(t, 0, 2); };
  auto IA_mh1 = [&](int t) { if constexpr (BM == 256) IA(t, 1, 3); else IA(t, 0, 1); };

  bf16x8 a[MH][2], b[4][2];
  auto DS_A = [&](int bb, int mh) {
#pragma unroll
    for (int m = 0; m < MH; ++m) {
      a[m][0] = *(const bf16x8*)(smem + bb + abase + (mh * MH + m) * 2048 + sa0);
      a[m][1] = *(const bf16x8*)(smem + bb + abase + (mh * MH + m) * 2048 + sa1);
    }
  };
  auto DS_B = [&](int bb, int nh) {
#pragma unroll
    for (int n = 0; n < 2; ++n) {
      b[nh * 2 + n][0] = *(const bf16x8*)(smem + bb + bbase + (nh * 2 + n) * 2048 + sa0);
      b[nh * 2 + n][1] = *(const bf16x8*)(smem + bb + bbase + (nh * 2 + n) * 2048 + sa1);
    }
  };
  auto MMA = [&](int mh, int nh) {
    __builtin_amdgcn_s_setprio(1);
#pragma unroll
    for (int m = 0; m < MH; ++m)
#pragma unroll
      for (int n = 0; n < 2; ++n)
#pragma unroll
        for (int ks = 0; ks < 2; ++ks)
          acc[mh * MH + m][nh * 2 + n] = __builtin_amdgcn_mfma_f32_16x16x32_bf16(
              a[m][ks], b[nh * 2 + n][ks], acc[mh * MH + m][nh * 2 + n], 0, 0, 0);
    __builtin_amdgcn_s_setprio(0);
  };

  // ---- prologue: tile0 fully + tile1 {A-mh0, B}; force tile0 landed.
  if constexpr (BM == 256) {
    IA(0, 0, 2); IB(0, 0); IB(0, 2); IA(0, 1, 3);
    IA(1, 0, 2); IB(1, 0); IB(1, 2);
    WAITV(6);
  } else {
    IB(0, 0); IB(0, 2); IA(0, 0, 1);
    IB(1, 0); IB(1, 2);
    WAITV(4);
  }
  BARX();

  for (int i = 0; i < niter; ++i) {
    const int t0 = 2 * i;
    const bool more = (i + 1 < niter);

    // ---- ph0: buf0 (mh0,nh0); stage A-mh1(t0+1)
    DS_A(0, 0); DS_B(0, 0);
    IA_mh1(t0 + 1);
    BARX(); WAITL(); MMA(0, 0); BARX();

    // ---- ph1: buf0 (mh0,nh1); stage A-mh0(t0+2)
    DS_B(0, 1);
    if (more) IA_mh0(t0 + 2);
    BARX(); WAITL(); MMA(0, 1); BARX();

    // ---- ph2: buf0 (mh1,nh0); stage B-lo(t0+2)
    DS_A(0, 1);
    if (more) IB(t0 + 2, 0);
    BARX(); WAITL(); MMA(1, 0); BARX();

    // ---- ph3: buf0 (mh1,nh1); stage B-hi(t0+2); certify tile t0+1
    if (more) IB(t0 + 2, 2);
    BARX(); MMA(1, 1);
    if (more) { if constexpr (BM == 256) WAITV(6); else WAITV(4); } else { WAITV(0); }
    BARX();

    // ---- ph4: buf1 (mh0,nh0); stage A-mh1(t0+2)
    DS_A(BUFSZ, 0); DS_B(BUFSZ, 0);
    if (more) IA_mh1(t0 + 2);
    BARX(); WAITL(); MMA(0, 0); BARX();

    // ---- ph5: buf1 (mh0,nh1); stage A-mh0(t0+3)
    DS_B(BUFSZ, 1);
    if (more) IA_mh0(t0 + 3);
    BARX(); WAITL(); MMA(0, 1); BARX();

    // ---- ph6: buf1 (mh1,nh0); stage B-lo(t0+3)
    DS_A(BUFSZ, 1);
    if (more) IB(t0 + 3, 0);
    BARX(); WAITL(); MMA(1, 0); BARX();

    // ---- ph7: buf1 (mh1,nh1); stage B-hi(t0+3); certify tile t0+2
    if (more) IB(t0 + 3, 2);
    BARX(); MMA(1, 1);
    if (more) { if constexpr (BM == 256) WAITV(6); else WAITV(4); } else { WAITV(0); }
    BARX();
  }

  // ---- epilogue. C/D map: col = lane&15, row = (lane>>4)*4 + reg
  const int c0 = bn0 + wc * 64 + lan15;
  if constexpr (OUTMODE == 0) {
    u16* C = (u16*)Cv;
    const int cb4 = (bn0 >> 8) * 4 + wc;  // partial-column index (0..127)
#pragma unroll
    for (int m = 0; m < MF; ++m)
#pragma unroll
      for (int r = 0; r < 4; ++r) {
        const int row = bm0 + wr * (BM / 2) + m * 16 + g * 4 + r;
        float part = 0.f;
#pragma unroll
        for (int n = 0; n < 4; ++n) {
          float v = __expf(acc[m][n][r] * scale);
          C[(size_t)row * ldc + c0 + n * 16] = f2bf(v);
          part += v;
        }
        part += __shfl_xor(part, 1, 64);
        part += __shfl_xor(part, 2, 64);
        part += __shfl_xor(part, 4, 64);
        part += __shfl_xor(part, 8, 64);
        if (lan15 == 0) partials[(size_t)row * 128 + cb4] = part;
      }
  } else {
    float* C = (float*)Cv;
#pragma unroll
    for (int m = 0; m < MF; ++m)
#pragma unroll
      for (int r = 0; r < 4; ++r) {
        const int row = bm0 + wr * (BM / 2) + m * 16 + g * 4 + r;
        const float iv = inv ? inv[row] : 1.0f;
#pragma unroll
        for (int n = 0; n < 4; ++n)
          C[(size_t)row * ldc + c0 + n * 16] = acc[m][n][r] * iv;
      }
  }
}

// ---------------- inv[row] = 1 / sum_j partials[row][j] --------------------
__global__ __launch_bounds__(256) void rowinv(const float* __restrict__ partials,
                                              float* __restrict__ inv) {
  const int row = blockIdx.x * 256 + threadIdx.x;
  const float4* p = (const float4*)(partials + (size_t)row * 128);
  float s = 0.f;
#pragma unroll
  for (int j = 0; j < 32; ++j) {
    float4 v = p[j];
    s += (v.x + v.y) + (v.z + v.w);
  }
  inv[row] = 1.0f / s;
}

// --------------- fallback: normalize E rows in place (bf16) ----------------
__global__ __launch_bounds__(256) void normalize_inplace(u16* __restrict__ E) {
  __shared__ float red[4];
  u16* row = E + (size_t)blockIdx.x * 8192;
  const int tid = threadIdx.x;
  float f[32];
  float s = 0.f;
#pragma unroll
  for (int c = 0; c < 4; ++c) {
    uint4 v = *((const uint4*)row + c * 256 + tid);
    unsigned u[4] = {v.x, v.y, v.z, v.w};
#pragma unroll
    for (int q = 0; q < 4; ++q) {
      f[c * 8 + q * 2] = bf2f((u16)(u[q] & 0xffffu));
      f[c * 8 + q * 2 + 1] = bf2f((u16)(u[q] >> 16));
      s += f[c * 8 + q * 2] + f[c * 8 + q * 2 + 1];
    }
  }
#pragma unroll
  for (int off = 32; off; off >>= 1) s += __shfl_xor(s, off, 64);
  if ((tid & 63) == 0) red[tid >> 6] = s;
  __syncthreads();
  const float iv = 1.0f / ((red[0] + red[1]) + (red[2] + red[3]));
#pragma unroll
  for (int c = 0; c < 4; ++c) {
    uint4 o;
    o.x = pack2(f[c * 8 + 0] * iv, f[c * 8 + 1] * iv);
    o.y = pack2(f[c * 8 + 2] * iv, f[c * 8 + 3] * iv);
    o.z = pack2(f[c * 8 + 4] * iv, f[c * 8 + 5] * iv);
    o.w = pack2(f[c * 8 + 6] * iv, f[c * 8 + 7] * iv);
    *((uint4*)row + c * 256 + tid) = o;
  }
}

// ---------------------------------------------------------------------------
extern "C" void kernel_launch(void* const* d_in, const int* in_sizes, int n_in,
                              void* d_out, int out_size, void* d_ws, size_t ws_size,
                              hipStream_t stream) {
  const float* Q = (const float*)d_in[0];
  const float* K = (const float*)d_in[1];
  const float* V = (const float*)d_in[2];

  char* ws = (char*)d_ws;
  u16* S = (u16*)ws;                                              // 128 MB
  u16* VT = (u16*)(ws + (size_t)134217728);                       // 16 MB
  float* partials = (float*)(ws + (size_t)134217728 + 16777216);  // 4 MB
  float* inv = (float*)(ws + (size_t)134217728 + 16777216 + 4194304);
  const bool haveInv =
      ws_size >= (size_t)134217728 + 16777216 + 4194304 + 32768;

  u16* Qb = (u16*)d_out;   // bf16 Q scratch (16 MB)
  u16* Kb = Qb + 8388608;  // bf16 K scratch (16 MB)

  cvt_bf16<<<4096, 256, 0, stream>>>(Q, Qb);
  cvt_bf16<<<4096, 256, 0, stream>>>(K, Kb);
  transpose_bf16<<<dim3(128, 16), 256, 0, stream>>>(V, VT);

  // E = exp(Q K^T / 32)  [8192 x 8192] bf16 ; BM=128, grid 2048 (DEC=2)
  gemm8d<128, 0, 2><<<2048, 512, 0, stream>>>(
      Qb, Kb, S, nullptr, haveInv ? partials : (float*)(ws + 134217728 + 16777216),
      1024, 8192, 1.0f / 32.0f);

  if (haveInv) {
    rowinv<<<32, 256, 0, stream>>>(partials, inv);
    // O = diag(inv) E V  [8192 x 1024] f32 ; grid 256 (stripe-sharing decode)
    gemm8d<128, 1, 1><<<256, 512, 0, stream>>>(
        S, VT, d_out, inv, nullptr, 8192, 1024, 1.0f);
  } else {
    normalize_inplace<<<8192, 256, 0, stream>>>(S);
    gemm8d<128, 1, 1><<<256, 512, 0, stream>>>(
        S, VT, d_out, nullptr, nullptr, 8192, 1024, 1.0f);
  }
}

// Round 16
// 307.321 us; speedup vs baseline: 1.0841x; 1.0841x over previous
//
#include <hip/hip_runtime.h>
#include <hip/hip_bf16.h>

// ---------------------------------------------------------------------------
// attention via: E = exp(QK^T/32) (bf16), inv[r] = 1/sum_k E[r,k] (per-wave
// partials), O = diag(inv)*E*V.
// r16 = compose the two best-measured kernels:
//   GEMM1: r11 pipelined-quadrant gemm_pl<256,DEPTH=2,DEC=0> — 146.9us
//          (best GEMM1 of 11 variants; supertile decode, FETCH 98MB).
//   GEMM2: gemm_pl<128,DEPTH=3,DEC=1> with r12's verified stripe decode
//          (8bm x 4bn per XCD chunk — cut FETCH 278->131MB, 146->121us on
//          the 8-phase kernel; decode is orthogonal to schedule).
// Schedule (r11, verified): per K-tile, 4 MFMA quadrants; every ds_read
// batch issued one quadrant before use (compiler counted-lgkm overlap);
// DMA staged DEPTH-1 tiles ahead, counted VM certify (never 0 mid-loop);
// ONE barrier per tile. T2 both-sides XOR swizzle (0 conflicts), T5 setprio.
// ws: [0,128MB)=E ; [128,144MB)=V^T ; [144,148MB)=partials ; then inv.
// d_out holds bf16 Q|K scratch until GEMM2 overwrites it.
// ---------------------------------------------------------------------------

typedef __bf16 bf16x8 __attribute__((ext_vector_type(8)));
typedef float f32x4 __attribute__((ext_vector_type(4)));
typedef const __attribute__((address_space(1))) unsigned int* as1p;
typedef __attribute__((address_space(3))) unsigned int* as3p;
typedef unsigned short u16;

__device__ __forceinline__ u16 f2bf(float x) {
  unsigned u = __float_as_uint(x);
  u += 0x7fffu + ((u >> 16) & 1u);
  return (u16)(u >> 16);
}
__device__ __forceinline__ float bf2f(u16 b) { return __uint_as_float(((unsigned)b) << 16); }
__device__ __forceinline__ unsigned pack2(float lo, float hi) {
  return (unsigned)f2bf(lo) | ((unsigned)f2bf(hi) << 16);
}

#define BAR()   do { __builtin_amdgcn_s_barrier(); asm volatile("" ::: "memory"); } while (0)
#define VM(n)   do { asm volatile("s_waitcnt vmcnt(" #n ")" ::: "memory"); __builtin_amdgcn_sched_barrier(0); } while (0)

// --------------------------- f32 -> bf16 convert ---------------------------
__global__ __launch_bounds__(256) void cvt_bf16(const float* __restrict__ in,
                                                unsigned short* __restrict__ out) {
  const size_t i = (size_t)blockIdx.x * 256 + threadIdx.x;
  const float4* p = (const float4*)in + i * 2;
  float4 a = p[0], b = p[1];
  uint4 o;
  o.x = pack2(a.x, a.y);
  o.y = pack2(a.z, a.w);
  o.z = pack2(b.x, b.y);
  o.w = pack2(b.z, b.w);
  ((uint4*)out)[i] = o;
}

// ------------- V [8192,1024] f32 -> V^T [1024,8192] bf16 -------------------
__global__ __launch_bounds__(256) void transpose_bf16(const float* __restrict__ V,
                                                      unsigned short* __restrict__ VT) {
  __shared__ float t[64][65];
  const int rb = blockIdx.x * 64;
  const int cb = blockIdx.y * 64;
  const int tid = threadIdx.x;
#pragma unroll
  for (int it = 0; it < 4; ++it) {
    int r = it * 16 + (tid >> 4);
    int c = (tid & 15) * 4;
    float4 x = *(const float4*)(V + (size_t)(rb + r) * 1024 + cb + c);
    t[r][c] = x.x; t[r][c + 1] = x.y; t[r][c + 2] = x.z; t[r][c + 3] = x.w;
  }
  __syncthreads();
  const int j = tid & 63;
  const int c0 = (tid >> 6) * 16;
#pragma unroll
  for (int i = 0; i < 16; ++i) {
    int c = c0 + i;
    VT[(size_t)(cb + c) * 8192 + rb + j] = f2bf(t[j][c]);
  }
}

// ---------------- pipelined quadrant NT GEMM (1 barrier/tile) --------------
// C[M,N](ldc) = A[M,K]*B[N,K]^T, BN=256. 512 threads, 8 waves (2M x 4N).
// DEC 0: grid 1024 = supertile 16bm x 8bn per XCD chunk   [GEMM1]
// DEC 1: grid 256  = 8bm x 4bn per XCD chunk, bn fastest  [GEMM2, r12 decode]
// OUTMODE 0: C=bf16 exp(acc*scale) + per-wave row partials.
// OUTMODE 1: C=f32 acc*inv[row].
template <int BM, int DEPTH, int OUTMODE, int DEC>
__global__ __launch_bounds__(512, 2) void gemm_pl(const u16* __restrict__ A,
                                                  const u16* __restrict__ B,
                                                  void* __restrict__ Cv,
                                                  const float* __restrict__ inv,
                                                  float* __restrict__ partials,
                                                  int K, int ldc, float scale) {
  constexpr int MF = BM / 32;       // per-wave m-frags (8 or 4)
  constexpr int MH = MF / 2;        // m-frags per half (4 or 2)
  constexpr int LAJ = BM / 64;      // A stage batches (4 or 2)
  constexpr int LPT = LAJ + 4;      // DMA loads/thread/tile (8 or 6)
  constexpr int ABUF = BM * 128;
  constexpr int BBUF = 32768;
  constexpr int BUFSZ = ABUF + BBUF;
  __shared__ __align__(1024) char smem[DEPTH * BUFSZ];

  const int tid = threadIdx.x;
  const int lane = tid & 63, wave = tid >> 6;
  const int wr = wave >> 2, wc = wave & 3;
  const int lan15 = lane & 15, g = lane >> 4, l7 = lane & 7;

  // T1: bijective XCD swizzle (nwg % 8 == 0 at both call sites)
  const int nwg = gridDim.x;
  const int wg = (blockIdx.x & 7) * (nwg >> 3) + (blockIdx.x >> 3);
  int bm0, bn0;
  if constexpr (DEC == 0) {
    const int r = wg & 255;
    bm0 = (r >> 3) * 256;
    bn0 = (((wg >> 8) << 3) | (r & 7)) * 256;
  } else {
    // r12-verified: XCD chunk of 32 = 8 bm x 4 bn, bn fastest -> the 4
    // blocks sharing an S-row-stripe sit on ONE XCD (L2 serves 3 of 4).
    const int chunk = wg >> 5;
    const int within = wg & 31;
    bm0 = (chunk * 8 + (within >> 2)) * BM;
    bn0 = (within & 3) * 256;
  }

  // staging: thread -> row (tid>>3), swizzled src col-block (tid&7)^(row&7)
  const int sr = tid >> 3;
  const int scb = ((tid & 7) ^ (sr & 7)) * 8;
  const u16* Ags = A + (size_t)(bm0 + sr) * K + scb;
  const u16* Bgs = B + (size_t)(bn0 + sr) * K + scb;

  // fragment-read swizzled 16B-slot offsets
  const int sa0 = ((0 + g) ^ l7) * 16;
  const int sa1 = ((4 + g) ^ l7) * 16;
  const int abase = (wr * (BM / 2) + lan15) * 128;
  const int bbase = ABUF + (wc * 64 + lan15) * 128;

  f32x4 acc[MF][4];
#pragma unroll
  for (int m = 0; m < MF; ++m)
#pragma unroll
    for (int n = 0; n < 4; ++n) acc[m][n] = f32x4{0.f, 0.f, 0.f, 0.f};

  const int nt = K >> 6;

  auto ISSUE = [&](int t) {
    char* bb = smem + (t % DEPTH) * BUFSZ;
    const size_t ko = (size_t)t * 64;
#pragma unroll
    for (int j = 0; j < LAJ; ++j)
      __builtin_amdgcn_global_load_lds((as1p)(Ags + (size_t)j * 64 * K + ko),
                                       (as3p)(bb + j * 8192 + tid * 16), 16, 0, 0);
#pragma unroll
    for (int j = 0; j < 4; ++j)
      __builtin_amdgcn_global_load_lds((as1p)(Bgs + (size_t)j * 64 * K + ko),
                                       (as3p)(bb + ABUF + j * 8192 + tid * 16), 16, 0, 0);
  };

  // fragment register sets
  bf16x8 A0[MH][2], A1[MH][2], B0[2][2], B1[2][2];

  auto RD_A0 = [&](int t) {
    const char* bp = smem + (t % DEPTH) * BUFSZ;
#pragma unroll
    for (int m = 0; m < MH; ++m) {
      A0[m][0] = *(const bf16x8*)(bp + abase + m * 2048 + sa0);
      A0[m][1] = *(const bf16x8*)(bp + abase + m * 2048 + sa1);
    }
  };
  auto RD_A1 = [&](int t) {
    const char* bp = smem + (t % DEPTH) * BUFSZ;
#pragma unroll
    for (int m = 0; m < MH; ++m) {
      A1[m][0] = *(const bf16x8*)(bp + abase + (MH + m) * 2048 + sa0);
      A1[m][1] = *(const bf16x8*)(bp + abase + (MH + m) * 2048 + sa1);
    }
  };
  auto RD_B0 = [&](int t) {
    const char* bp = smem + (t % DEPTH) * BUFSZ;
#pragma unroll
    for (int n = 0; n < 2; ++n) {
      B0[n][0] = *(const bf16x8*)(bp + bbase + n * 2048 + sa0);
      B0[n][1] = *(const bf16x8*)(bp + bbase + n * 2048 + sa1);
    }
  };
  auto RD_B1 = [&](int t) {
    const char* bp = smem + (t % DEPTH) * BUFSZ;
#pragma unroll
    for (int n = 0; n < 2; ++n) {
      B1[n][0] = *(const bf16x8*)(bp + bbase + (2 + n) * 2048 + sa0);
      B1[n][1] = *(const bf16x8*)(bp + bbase + (2 + n) * 2048 + sa1);
    }
  };

  auto Q = [&](bf16x8 (&a)[MH][2], bf16x8 (&b)[2][2], int mo, int no) {
    __builtin_amdgcn_s_setprio(1);
#pragma unroll
    for (int m = 0; m < MH; ++m)
#pragma unroll
      for (int n = 0; n < 2; ++n)
#pragma unroll
        for (int ks = 0; ks < 2; ++ks)
          acc[mo + m][no + n] = __builtin_amdgcn_mfma_f32_16x16x32_bf16(
              a[m][ks], b[n][ks], acc[mo + m][no + n], 0, 0, 0);
    __builtin_amdgcn_s_setprio(0);
  };

  // ---- prologue: stage buf0 (+buf1 at DEPTH=3); certify buf0; read Q0 set
  ISSUE(0);
  if constexpr (DEPTH == 3) {
    ISSUE(1);
    if constexpr (LPT == 8) { VM(8); } else { VM(6); }
  } else {
    VM(0);
  }
  BAR();
  RD_A0(0); RD_B0(0);

  for (int t = 0; t < nt; ++t) {
    BAR();  // all waves done reading buf((t-1)%D) -> safe to overwrite
    if constexpr (DEPTH == 2) {
      if (t + 1 < nt) ISSUE(t + 1);
    } else {
      if (t + 2 < nt) ISSUE(t + 2);
    }
    RD_B1(t);
    Q(A0, B0, 0, 0);   // compiler waits A0,B0 (issued prev Q3), B1 in flight
    RD_A1(t);
    Q(A0, B1, 0, 2);
    // certify buf(t+1) DMA landed (counted at DEPTH=3: t+2 stays in flight)
    if constexpr (DEPTH == 2) {
      if (t + 1 < nt) { VM(0); }
    } else {
      if (t + 2 < nt) {
        if constexpr (LPT == 8) { VM(8); } else { VM(6); }
      } else if (t + 1 < nt) {
        VM(0);
      }
    }
    Q(A1, B0, MH, 0);
    if (t + 1 < nt) { RD_A0(t + 1); RD_B0(t + 1); }  // buf(t+1) certified
    Q(A1, B1, MH, 2);
  }

  // ---- epilogue. C/D map: col = lane&15, row = (lane>>4)*4 + reg
  const int c0 = bn0 + wc * 64 + lan15;
  if constexpr (OUTMODE == 0) {
    u16* C = (u16*)Cv;
    const int cb4 = (bn0 >> 8) * 4 + wc;  // partial-column index (0..127)
#pragma unroll
    for (int m = 0; m < MF; ++m)
#pragma unroll
      for (int r = 0; r < 4; ++r) {
        const int row = bm0 + wr * (BM / 2) + m * 16 + g * 4 + r;
        float part = 0.f;
#pragma unroll
        for (int n = 0; n < 4; ++n) {
          float v = __expf(acc[m][n][r] * scale);
          C[(size_t)row * ldc + c0 + n * 16] = f2bf(v);
          part += v;
        }
        part += __shfl_xor(part, 1, 64);
        part += __shfl_xor(part, 2, 64);
        part += __shfl_xor(part, 4, 64);
        part += __shfl_xor(part, 8, 64);
        if (lan15 == 0) partials[(size_t)row * 128 + cb4] = part;
      }
  } else {
    float* C = (float*)Cv;
#pragma unroll
    for (int m = 0; m < MF; ++m)
#pragma unroll
      for (int r = 0; r < 4; ++r) {
        const int row = bm0 + wr * (BM / 2) + m * 16 + g * 4 + r;
        const float iv = inv ? inv[row] : 1.0f;
#pragma unroll
        for (int n = 0; n < 4; ++n)
          C[(size_t)row * ldc + c0 + n * 16] = acc[m][n][r] * iv;
      }
  }
}

// ---------------- inv[row] = 1 / sum_j partials[row][j] --------------------
__global__ __launch_bounds__(256) void rowinv(const float* __restrict__ partials,
                                              float* __restrict__ inv) {
  const int row = blockIdx.x * 256 + threadIdx.x;
  const float4* p = (const float4*)(partials + (size_t)row * 128);
  float s = 0.f;
#pragma unroll
  for (int j = 0; j < 32; ++j) {
    float4 v = p[j];
    s += (v.x + v.y) + (v.z + v.w);
  }
  inv[row] = 1.0f / s;
}

// --------------- fallback: normalize E rows in place (bf16) ----------------
__global__ __launch_bounds__(256) void normalize_inplace(u16* __restrict__ E) {
  __shared__ float red[4];
  u16* row = E + (size_t)blockIdx.x * 8192;
  const int tid = threadIdx.x;
  float f[32];
  float s = 0.f;
#pragma unroll
  for (int c = 0; c < 4; ++c) {
    uint4 v = *((const uint4*)row + c * 256 + tid);
    unsigned u[4] = {v.x, v.y, v.z, v.w};
#pragma unroll
    for (int q = 0; q < 4; ++q) {
      f[c * 8 + q * 2] = bf2f((u16)(u[q] & 0xffffu));
      f[c * 8 + q * 2 + 1] = bf2f((u16)(u[q] >> 16));
      s += f[c * 8 + q * 2] + f[c * 8 + q * 2 + 1];
    }
  }
#pragma unroll
  for (int off = 32; off; off >>= 1) s += __shfl_xor(s, off, 64);
  if ((tid & 63) == 0) red[tid >> 6] = s;
  __syncthreads();
  const float iv = 1.0f / ((red[0] + red[1]) + (red[2] + red[3]));
#pragma unroll
  for (int c = 0; c < 4; ++c) {
    uint4 o;
    o.x = pack2(f[c * 8 + 0] * iv, f[c * 8 + 1] * iv);
    o.y = pack2(f[c * 8 + 2] * iv, f[c * 8 + 3] * iv);
    o.z = pack2(f[c * 8 + 4] * iv, f[c * 8 + 5] * iv);
    o.w = pack2(f[c * 8 + 6] * iv, f[c * 8 + 7] * iv);
    *((uint4*)row + c * 256 + tid) = o;
  }
}

// ---------------------------------------------------------------------------
extern "C" void kernel_launch(void* const* d_in, const int* in_sizes, int n_in,
                              void* d_out, int out_size, void* d_ws, size_t ws_size,
                              hipStream_t stream) {
  const float* Q = (const float*)d_in[0];
  const float* K = (const float*)d_in[1];
  const float* V = (const float*)d_in[2];

  char* ws = (char*)d_ws;
  u16* S = (u16*)ws;                                              // 128 MB
  u16* VT = (u16*)(ws + (size_t)134217728);                       // 16 MB
  float* partials = (float*)(ws + (size_t)134217728 + 16777216);  // 4 MB
  float* inv = (float*)(ws + (size_t)134217728 + 16777216 + 4194304);
  const bool haveInv =
      ws_size >= (size_t)134217728 + 16777216 + 4194304 + 32768;

  u16* Qb = (u16*)d_out;   // bf16 Q scratch (16 MB)
  u16* Kb = Qb + 8388608;  // bf16 K scratch (16 MB)

  cvt_bf16<<<4096, 256, 0, stream>>>(Q, Qb);
  cvt_bf16<<<4096, 256, 0, stream>>>(K, Kb);
  transpose_bf16<<<dim3(128, 16), 256, 0, stream>>>(V, VT);

  // E = exp(Q K^T / 32)  [8192 x 8192] bf16 ; grid 1024 (supertile decode)
  gemm_pl<256, 2, 0, 0><<<1024, 512, 0, stream>>>(
      Qb, Kb, S, nullptr, haveInv ? partials : (float*)(ws + 134217728 + 16777216),
      1024, 8192, 1.0f / 32.0f);

  if (haveInv) {
    rowinv<<<32, 256, 0, stream>>>(partials, inv);
    // O = diag(inv) E V  [8192 x 1024] f32 ; grid 256 (stripe decode)
    gemm_pl<128, 3, 1, 1><<<256, 512, 0, stream>>>(
        S, VT, d_out, inv, nullptr, 8192, 1024, 1.0f);
  } else {
    normalize_inplace<<<8192, 256, 0, stream>>>(S);
    gemm_pl<128, 3, 1, 1><<<256, 512, 0, stream>>>(
        S, VT, d_out, nullptr, nullptr, 8192, 1024, 1.0f);
  }
}

// Round 17
// 303.724 us; speedup vs baseline: 1.0969x; 1.0118x over previous
//
#include <hip/hip_runtime.h>
#include <hip/hip_bf16.h>

// ---------------------------------------------------------------------------
// attention via: E = exp(QK^T/32) (bf16), inv[r] = 1/sum_k E[r,k] (per-wave
// partials), O = diag(inv)*E*V.
// r17 = cross-pair the measured bests (never yet run together):
//   GEMM1: gemm_pl<256,DEPTH=2,DEC=0>  (r11/r16: ~138-147us, FETCH 98MB)
//          pipelined-quadrant schedule, supertile decode.
//   GEMM2: gemm8d<128,OUT=1,DEC=1>     (r12/r13: ~121us, FETCH 131MB)
//          8-phase 2-tile-ahead schedule, stripe decode.
// r16 showed the schedules are NOT interchangeable per-operand (gemm_pl on
// GEMM2 = 147us vs gemm8d 121us at same decode); this pairs each GEMM with
// the schedule that measured fastest for it. Both kernels verbatim from
// their verified rounds (absmax 0.0004882812 expected unchanged).
// ws: [0,128MB)=E ; [128,144MB)=V^T ; [144,148MB)=partials ; then inv.
// d_out holds bf16 Q|K scratch until GEMM2 overwrites it.
// ---------------------------------------------------------------------------

typedef __bf16 bf16x8 __attribute__((ext_vector_type(8)));
typedef float f32x4 __attribute__((ext_vector_type(4)));
typedef const __attribute__((address_space(1))) unsigned int* as1p;
typedef __attribute__((address_space(3))) unsigned int* as3p;
typedef unsigned short u16;

__device__ __forceinline__ u16 f2bf(float x) {
  unsigned u = __float_as_uint(x);
  u += 0x7fffu + ((u >> 16) & 1u);
  return (u16)(u >> 16);
}
__device__ __forceinline__ float bf2f(u16 b) { return __uint_as_float(((unsigned)b) << 16); }
__device__ __forceinline__ unsigned pack2(float lo, float hi) {
  return (unsigned)f2bf(lo) | ((unsigned)f2bf(hi) << 16);
}

// gemm_pl sync family (r11, measured)
#define BAR()   do { __builtin_amdgcn_s_barrier(); asm volatile("" ::: "memory"); } while (0)
#define VM(n)   do { asm volatile("s_waitcnt vmcnt(" #n ")" ::: "memory"); __builtin_amdgcn_sched_barrier(0); } while (0)
// gemm8d sync family (r13, measured)
#define BARX()   __builtin_amdgcn_s_barrier()
#define WAITL()  asm volatile("s_waitcnt lgkmcnt(0)")
#define WAITV(n) asm volatile("s_waitcnt vmcnt(" #n ")")

// --------------------------- f32 -> bf16 convert ---------------------------
__global__ __launch_bounds__(256) void cvt_bf16(const float* __restrict__ in,
                                                unsigned short* __restrict__ out) {
  const size_t i = (size_t)blockIdx.x * 256 + threadIdx.x;
  const float4* p = (const float4*)in + i * 2;
  float4 a = p[0], b = p[1];
  uint4 o;
  o.x = pack2(a.x, a.y);
  o.y = pack2(a.z, a.w);
  o.z = pack2(b.x, b.y);
  o.w = pack2(b.z, b.w);
  ((uint4*)out)[i] = o;
}

// ------------- V [8192,1024] f32 -> V^T [1024,8192] bf16 -------------------
__global__ __launch_bounds__(256) void transpose_bf16(const float* __restrict__ V,
                                                      unsigned short* __restrict__ VT) {
  __shared__ float t[64][65];
  const int rb = blockIdx.x * 64;
  const int cb = blockIdx.y * 64;
  const int tid = threadIdx.x;
#pragma unroll
  for (int it = 0; it < 4; ++it) {
    int r = it * 16 + (tid >> 4);
    int c = (tid & 15) * 4;
    float4 x = *(const float4*)(V + (size_t)(rb + r) * 1024 + cb + c);
    t[r][c] = x.x; t[r][c + 1] = x.y; t[r][c + 2] = x.z; t[r][c + 3] = x.w;
  }
  __syncthreads();
  const int j = tid & 63;
  const int c0 = (tid >> 6) * 16;
#pragma unroll
  for (int i = 0; i < 16; ++i) {
    int c = c0 + i;
    VT[(size_t)(cb + c) * 8192 + rb + j] = f2bf(t[j][c]);
  }
}

// ============ GEMM1: pipelined quadrant NT GEMM (r11, verbatim) ============
// C[M,N](ldc) = A[M,K]*B[N,K]^T, BN=256. 512 threads, 8 waves (2M x 4N).
// DEC 0: grid 1024 = supertile 16bm x 8bn per XCD chunk.
// OUTMODE 0: C=bf16 exp(acc*scale) + per-wave row partials.
template <int BM, int DEPTH, int OUTMODE, int DEC>
__global__ __launch_bounds__(512, 2) void gemm_pl(const u16* __restrict__ A,
                                                  const u16* __restrict__ B,
                                                  void* __restrict__ Cv,
                                                  const float* __restrict__ inv,
                                                  float* __restrict__ partials,
                                                  int K, int ldc, float scale) {
  constexpr int MF = BM / 32;
  constexpr int MH = MF / 2;
  constexpr int LAJ = BM / 64;
  constexpr int LPT = LAJ + 4;
  constexpr int ABUF = BM * 128;
  constexpr int BBUF = 32768;
  constexpr int BUFSZ = ABUF + BBUF;
  __shared__ __align__(1024) char smem[DEPTH * BUFSZ];

  const int tid = threadIdx.x;
  const int lane = tid & 63, wave = tid >> 6;
  const int wr = wave >> 2, wc = wave & 3;
  const int lan15 = lane & 15, g = lane >> 4, l7 = lane & 7;

  const int nwg = gridDim.x;
  const int wg = (blockIdx.x & 7) * (nwg >> 3) + (blockIdx.x >> 3);
  int bm0, bn0;
  if constexpr (DEC == 0) {
    const int r = wg & 255;
    bm0 = (r >> 3) * 256;
    bn0 = (((wg >> 8) << 3) | (r & 7)) * 256;
  } else {
    const int chunk = wg >> 5;
    const int within = wg & 31;
    bm0 = (chunk * 8 + (within >> 2)) * BM;
    bn0 = (within & 3) * 256;
  }

  const int sr = tid >> 3;
  const int scb = ((tid & 7) ^ (sr & 7)) * 8;
  const u16* Ags = A + (size_t)(bm0 + sr) * K + scb;
  const u16* Bgs = B + (size_t)(bn0 + sr) * K + scb;

  const int sa0 = ((0 + g) ^ l7) * 16;
  const int sa1 = ((4 + g) ^ l7) * 16;
  const int abase = (wr * (BM / 2) + lan15) * 128;
  const int bbase = ABUF + (wc * 64 + lan15) * 128;

  f32x4 acc[MF][4];
#pragma unroll
  for (int m = 0; m < MF; ++m)
#pragma unroll
    for (int n = 0; n < 4; ++n) acc[m][n] = f32x4{0.f, 0.f, 0.f, 0.f};

  const int nt = K >> 6;

  auto ISSUE = [&](int t) {
    char* bb = smem + (t % DEPTH) * BUFSZ;
    const size_t ko = (size_t)t * 64;
#pragma unroll
    for (int j = 0; j < LAJ; ++j)
      __builtin_amdgcn_global_load_lds((as1p)(Ags + (size_t)j * 64 * K + ko),
                                       (as3p)(bb + j * 8192 + tid * 16), 16, 0, 0);
#pragma unroll
    for (int j = 0; j < 4; ++j)
      __builtin_amdgcn_global_load_lds((as1p)(Bgs + (size_t)j * 64 * K + ko),
                                       (as3p)(bb + ABUF + j * 8192 + tid * 16), 16, 0, 0);
  };

  bf16x8 A0[MH][2], A1[MH][2], B0[2][2], B1[2][2];

  auto RD_A0 = [&](int t) {
    const char* bp = smem + (t % DEPTH) * BUFSZ;
#pragma unroll
    for (int m = 0; m < MH; ++m) {
      A0[m][0] = *(const bf16x8*)(bp + abase + m * 2048 + sa0);
      A0[m][1] = *(const bf16x8*)(bp + abase + m * 2048 + sa1);
    }
  };
  auto RD_A1 = [&](int t) {
    const char* bp = smem + (t % DEPTH) * BUFSZ;
#pragma unroll
    for (int m = 0; m < MH; ++m) {
      A1[m][0] = *(const bf16x8*)(bp + abase + (MH + m) * 2048 + sa0);
      A1[m][1] = *(const bf16x8*)(bp + abase + (MH + m) * 2048 + sa1);
    }
  };
  auto RD_B0 = [&](int t) {
    const char* bp = smem + (t % DEPTH) * BUFSZ;
#pragma unroll
    for (int n = 0; n < 2; ++n) {
      B0[n][0] = *(const bf16x8*)(bp + bbase + n * 2048 + sa0);
      B0[n][1] = *(const bf16x8*)(bp + bbase + n * 2048 + sa1);
    }
  };
  auto RD_B1 = [&](int t) {
    const char* bp = smem + (t % DEPTH) * BUFSZ;
#pragma unroll
    for (int n = 0; n < 2; ++n) {
      B1[n][0] = *(const bf16x8*)(bp + bbase + (2 + n) * 2048 + sa0);
      B1[n][1] = *(const bf16x8*)(bp + bbase + (2 + n) * 2048 + sa1);
    }
  };

  auto Q = [&](bf16x8 (&a)[MH][2], bf16x8 (&b)[2][2], int mo, int no) {
    __builtin_amdgcn_s_setprio(1);
#pragma unroll
    for (int m = 0; m < MH; ++m)
#pragma unroll
      for (int n = 0; n < 2; ++n)
#pragma unroll
        for (int ks = 0; ks < 2; ++ks)
          acc[mo + m][no + n] = __builtin_amdgcn_mfma_f32_16x16x32_bf16(
              a[m][ks], b[n][ks], acc[mo + m][no + n], 0, 0, 0);
    __builtin_amdgcn_s_setprio(0);
  };

  ISSUE(0);
  if constexpr (DEPTH == 3) {
    ISSUE(1);
    if constexpr (LPT == 8) { VM(8); } else { VM(6); }
  } else {
    VM(0);
  }
  BAR();
  RD_A0(0); RD_B0(0);

  for (int t = 0; t < nt; ++t) {
    BAR();
    if constexpr (DEPTH == 2) {
      if (t + 1 < nt) ISSUE(t + 1);
    } else {
      if (t + 2 < nt) ISSUE(t + 2);
    }
    RD_B1(t);
    Q(A0, B0, 0, 0);
    RD_A1(t);
    Q(A0, B1, 0, 2);
    if constexpr (DEPTH == 2) {
      if (t + 1 < nt) { VM(0); }
    } else {
      if (t + 2 < nt) {
        if constexpr (LPT == 8) { VM(8); } else { VM(6); }
      } else if (t + 1 < nt) {
        VM(0);
      }
    }
    Q(A1, B0, MH, 0);
    if (t + 1 < nt) { RD_A0(t + 1); RD_B0(t + 1); }
    Q(A1, B1, MH, 2);
  }

  const int c0 = bn0 + wc * 64 + lan15;
  if constexpr (OUTMODE == 0) {
    u16* C = (u16*)Cv;
    const int cb4 = (bn0 >> 8) * 4 + wc;
#pragma unroll
    for (int m = 0; m < MF; ++m)
#pragma unroll
      for (int r = 0; r < 4; ++r) {
        const int row = bm0 + wr * (BM / 2) + m * 16 + g * 4 + r;
        float part = 0.f;
#pragma unroll
        for (int n = 0; n < 4; ++n) {
          float v = __expf(acc[m][n][r] * scale);
          C[(size_t)row * ldc + c0 + n * 16] = f2bf(v);
          part += v;
        }
        part += __shfl_xor(part, 1, 64);
        part += __shfl_xor(part, 2, 64);
        part += __shfl_xor(part, 4, 64);
        part += __shfl_xor(part, 8, 64);
        if (lan15 == 0) partials[(size_t)row * 128 + cb4] = part;
      }
  } else {
    float* C = (float*)Cv;
#pragma unroll
    for (int m = 0; m < MF; ++m)
#pragma unroll
      for (int r = 0; r < 4; ++r) {
        const int row = bm0 + wr * (BM / 2) + m * 16 + g * 4 + r;
        const float iv = inv ? inv[row] : 1.0f;
#pragma unroll
        for (int n = 0; n < 4; ++n)
          C[(size_t)row * ldc + c0 + n * 16] = acc[m][n][r] * iv;
      }
  }
}

// ============ GEMM2: 8-phase NT GEMM (r13, verbatim) =======================
// C[M,N](ldc) = A[M,K]*B[N,K]^T, BN=256, BM=128. 8 phases / 2 K-tiles,
// 2-tile-ahead staging into dead regions, counted WAITV(4) at ph3/ph7.
// DEC 1: grid 256 = 8bm x 4bn per XCD chunk (bn fastest).
template <int BM, int OUTMODE, int DEC>
__global__ __launch_bounds__(512, 2) void gemm8d(const u16* __restrict__ A,
                                                 const u16* __restrict__ B,
                                                 void* __restrict__ Cv,
                                                 const float* __restrict__ inv,
                                                 float* __restrict__ partials,
                                                 int K, int ldc, float scale) {
  constexpr int MF = BM / 32;
  constexpr int MH = MF / 2;
  constexpr int ABUF = BM * 128;
  constexpr int BBUF = 32768;
  constexpr int BUFSZ = ABUF + BBUF;
  __shared__ __align__(1024) char smem[2 * BUFSZ];

  const int tid = threadIdx.x;
  const int lane = tid & 63, wave = tid >> 6;
  const int wr = wave >> 2, wc = wave & 3;
  const int lan15 = lane & 15, g = lane >> 4, l7 = lane & 7;

  const int nwg = gridDim.x;
  const int wg = (blockIdx.x & 7) * (nwg >> 3) + (blockIdx.x >> 3);
  int bm0, bn0;
  if constexpr (DEC == 0) {
    const int r = wg & 255;
    bm0 = (r >> 3) * 256;
    bn0 = (((wg >> 8) << 3) | (r & 7)) * 256;
  } else {
    const int chunk = wg >> 5;
    const int within = wg & 31;
    bm0 = (chunk * 8 + (within >> 2)) * BM;
    bn0 = (within & 3) * 256;
  }

  const int sr = tid >> 3;
  const int scb = ((tid & 7) ^ (sr & 7)) * 8;
  const u16* Ags = A + (size_t)(bm0 + sr) * K + scb;
  const u16* Bgs = B + (size_t)(bn0 + sr) * K + scb;

  const int sa0 = ((0 + g) ^ l7) * 16;
  const int sa1 = ((4 + g) ^ l7) * 16;
  const int abase = (wr * (BM / 2) + lan15) * 128;
  const int bbase = ABUF + (wc * 64 + lan15) * 128;

  f32x4 acc[MF][4];
#pragma unroll
  for (int m = 0; m < MF; ++m)
#pragma unroll
    for (int n = 0; n < 4; ++n) acc[m][n] = f32x4{0.f, 0.f, 0.f, 0.f};

  const int nt = K >> 6;
  const int niter = nt >> 1;

  auto IA = [&](int t, int ja, int jb) {
    char* bb = smem + (t & 1) * BUFSZ;
    const size_t ko = (size_t)t * 64;
    __builtin_amdgcn_global_load_lds((as1p)(Ags + (size_t)ja * 64 * K + ko),
                                     (as3p)(bb + ja * 8192 + tid * 16), 16, 0, 0);
    __builtin_amdgcn_global_load_lds((as1p)(Ags + (size_t)jb * 64 * K + ko),
                                     (as3p)(bb + jb * 8192 + tid * 16), 16, 0, 0);
  };
  auto IB = [&](int t, int j0) {
    char* bb = smem + (t & 1) * BUFSZ + ABUF;
    const size_t ko = (size_t)t * 64;
    __builtin_amdgcn_global_load_lds((as1p)(Bgs + (size_t)j0 * 64 * K + ko),
                                     (as3p)(bb + j0 * 8192 + tid * 16), 16, 0, 0);
    __builtin_amdgcn_global_load_lds((as1p)(Bgs + (size_t)(j0 + 1) * 64 * K + ko),
                                     (as3p)(bb + (j0 + 1) * 8192 + tid * 16), 16, 0, 0);
  };
  auto IA_mh0 = [&](int t) { if constexpr (BM == 256) IA(t, 0, 2); };
  auto IA_mh1 = [&](int t) { if constexpr (BM == 256) IA(t, 1, 3); else IA(t, 0, 1); };

  bf16x8 a[MH][2], b[4][2];
  auto DS_A = [&](int bb, int mh) {
#pragma unroll
    for (int m = 0; m < MH; ++m) {
      a[m][0] = *(const bf16x8*)(smem + bb + abase + (mh * MH + m) * 2048 + sa0);
      a[m][1] = *(const bf16x8*)(smem + bb + abase + (mh * MH + m) * 2048 + sa1);
    }
  };
  auto DS_B = [&](int bb, int nh) {
#pragma unroll
    for (int n = 0; n < 2; ++n) {
      b[nh * 2 + n][0] = *(const bf16x8*)(smem + bb + bbase + (nh * 2 + n) * 2048 + sa0);
      b[nh * 2 + n][1] = *(const bf16x8*)(smem + bb + bbase + (nh * 2 + n) * 2048 + sa1);
    }
  };
  auto MMA = [&](int mh, int nh) {
    __builtin_amdgcn_s_setprio(1);
#pragma unroll
    for (int m = 0; m < MH; ++m)
#pragma unroll
      for (int n = 0; n < 2; ++n)
#pragma unroll
        for (int ks = 0; ks < 2; ++ks)
          acc[mh * MH + m][nh * 2 + n] = __builtin_amdgcn_mfma_f32_16x16x32_bf16(
              a[m][ks], b[nh * 2 + n][ks], acc[mh * MH + m][nh * 2 + n], 0, 0, 0);
    __builtin_amdgcn_s_setprio(0);
  };

  if constexpr (BM == 256) {
    IA(0, 0, 2); IB(0, 0); IB(0, 2); IA(0, 1, 3);
    IA(1, 0, 2); IB(1, 0); IB(1, 2);
    WAITV(6);
  } else {
    IB(0, 0); IB(0, 2); IA(0, 0, 1);
    IB(1, 0); IB(1, 2);
    WAITV(4);
  }
  BARX();

  for (int i = 0; i < niter; ++i) {
    const int t0 = 2 * i;
    const bool more = (i + 1 < niter);

    DS_A(0, 0); DS_B(0, 0);
    IA_mh1(t0 + 1);
    BARX(); WAITL(); MMA(0, 0); BARX();

    DS_B(0, 1);
    if (more) IA_mh0(t0 + 2);
    BARX(); WAITL(); MMA(0, 1); BARX();

    DS_A(0, 1);
    if (more) IB(t0 + 2, 0);
    BARX(); WAITL(); MMA(1, 0); BARX();

    if (more) IB(t0 + 2, 2);
    BARX(); MMA(1, 1);
    if (more) { if constexpr (BM == 256) WAITV(6); else WAITV(4); } else { WAITV(0); }
    BARX();

    DS_A(BUFSZ, 0); DS_B(BUFSZ, 0);
    if (more) IA_mh1(t0 + 2);
    BARX(); WAITL(); MMA(0, 0); BARX();

    DS_B(BUFSZ, 1);
    if (more) IA_mh0(t0 + 3);
    BARX(); WAITL(); MMA(0, 1); BARX();

    DS_A(BUFSZ, 1);
    if (more) IB(t0 + 3, 0);
    BARX(); WAITL(); MMA(1, 0); BARX();

    if (more) IB(t0 + 3, 2);
    BARX(); MMA(1, 1);
    if (more) { if constexpr (BM == 256) WAITV(6); else WAITV(4); } else { WAITV(0); }
    BARX();
  }

  const int c0 = bn0 + wc * 64 + lan15;
  if constexpr (OUTMODE == 0) {
    u16* C = (u16*)Cv;
    const int cb4 = (bn0 >> 8) * 4 + wc;
#pragma unroll
    for (int m = 0; m < MF; ++m)
#pragma unroll
      for (int r = 0; r < 4; ++r) {
        const int row = bm0 + wr * (BM / 2) + m * 16 + g * 4 + r;
        float part = 0.f;
#pragma unroll
        for (int n = 0; n < 4; ++n) {
          float v = __expf(acc[m][n][r] * scale);
          C[(size_t)row * ldc + c0 + n * 16] = f2bf(v);
          part += v;
        }
        part += __shfl_xor(part, 1, 64);
        part += __shfl_xor(part, 2, 64);
        part += __shfl_xor(part, 4, 64);
        part += __shfl_xor(part, 8, 64);
        if (lan15 == 0) partials[(size_t)row * 128 + cb4] = part;
      }
  } else {
    float* C = (float*)Cv;
#pragma unroll
    for (int m = 0; m < MF; ++m)
#pragma unroll
      for (int r = 0; r < 4; ++r) {
        const int row = bm0 + wr * (BM / 2) + m * 16 + g * 4 + r;
        const float iv = inv ? inv[row] : 1.0f;
#pragma unroll
        for (int n = 0; n < 4; ++n)
          C[(size_t)row * ldc + c0 + n * 16] = acc[m][n][r] * iv;
      }
  }
}

// ---------------- inv[row] = 1 / sum_j partials[row][j] --------------------
__global__ __launch_bounds__(256) void rowinv(const float* __restrict__ partials,
                                              float* __restrict__ inv) {
  const int row = blockIdx.x * 256 + threadIdx.x;
  const float4* p = (const float4*)(partials + (size_t)row * 128);
  float s = 0.f;
#pragma unroll
  for (int j = 0; j < 32; ++j) {
    float4 v = p[j];
    s += (v.x + v.y) + (v.z + v.w);
  }
  inv[row] = 1.0f / s;
}

// --------------- fallback: normalize E rows in place (bf16) ----------------
__global__ __launch_bounds__(256) void normalize_inplace(u16* __restrict__ E) {
  __shared__ float red[4];
  u16* row = E + (size_t)blockIdx.x * 8192;
  const int tid = threadIdx.x;
  float f[32];
  float s = 0.f;
#pragma unroll
  for (int c = 0; c < 4; ++c) {
    uint4 v = *((const uint4*)row + c * 256 + tid);
    unsigned u[4] = {v.x, v.y, v.z, v.w};
#pragma unroll
    for (int q = 0; q < 4; ++q) {
      f[c * 8 + q * 2] = bf2f((u16)(u[q] & 0xffffu));
      f[c * 8 + q * 2 + 1] = bf2f((u16)(u[q] >> 16));
      s += f[c * 8 + q * 2] + f[c * 8 + q * 2 + 1];
    }
  }
#pragma unroll
  for (int off = 32; off; off >>= 1) s += __shfl_xor(s, off, 64);
  if ((tid & 63) == 0) red[tid >> 6] = s;
  __syncthreads();
  const float iv = 1.0f / ((red[0] + red[1]) + (red[2] + red[3]));
#pragma unroll
  for (int c = 0; c < 4; ++c) {
    uint4 o;
    o.x = pack2(f[c * 8 + 0] * iv, f[c * 8 + 1] * iv);
    o.y = pack2(f[c * 8 + 2] * iv, f[c * 8 + 3] * iv);
    o.z = pack2(f[c * 8 + 4] * iv, f[c * 8 + 5] * iv);
    o.w = pack2(f[c * 8 + 6] * iv, f[c * 8 + 7] * iv);
    *((uint4*)row + c * 256 + tid) = o;
  }
}

// ---------------------------------------------------------------------------
extern "C" void kernel_launch(void* const* d_in, const int* in_sizes, int n_in,
                              void* d_out, int out_size, void* d_ws, size_t ws_size,
                              hipStream_t stream) {
  const float* Q = (const float*)d_in[0];
  const float* K = (const float*)d_in[1];
  const float* V = (const float*)d_in[2];

  char* ws = (char*)d_ws;
  u16* S = (u16*)ws;                                              // 128 MB
  u16* VT = (u16*)(ws + (size_t)134217728);                       // 16 MB
  float* partials = (float*)(ws + (size_t)134217728 + 16777216);  // 4 MB
  float* inv = (float*)(ws + (size_t)134217728 + 16777216 + 4194304);
  const bool haveInv =
      ws_size >= (size_t)134217728 + 16777216 + 4194304 + 32768;

  u16* Qb = (u16*)d_out;   // bf16 Q scratch (16 MB)
  u16* Kb = Qb + 8388608;  // bf16 K scratch (16 MB)

  cvt_bf16<<<4096, 256, 0, stream>>>(Q, Qb);
  cvt_bf16<<<4096, 256, 0, stream>>>(K, Kb);
  transpose_bf16<<<dim3(128, 16), 256, 0, stream>>>(V, VT);

  // E = exp(Q K^T / 32)  [8192 x 8192] bf16 ; quadrant schedule, supertile
  gemm_pl<256, 2, 0, 0><<<1024, 512, 0, stream>>>(
      Qb, Kb, S, nullptr, haveInv ? partials : (float*)(ws + 134217728 + 16777216),
      1024, 8192, 1.0f / 32.0f);

  if (haveInv) {
    rowinv<<<32, 256, 0, stream>>>(partials, inv);
    // O = diag(inv) E V  [8192 x 1024] f32 ; 8-phase schedule, stripe decode
    gemm8d<128, 1, 1><<<256, 512, 0, stream>>>(
        S, VT, d_out, inv, nullptr, 8192, 1024, 1.0f);
  } else {
    normalize_inplace<<<8192, 256, 0, stream>>>(S);
    gemm8d<128, 1, 1><<<256, 512, 0, stream>>>(
        S, VT, d_out, nullptr, nullptr, 8192, 1024, 1.0f);
  }
}

// Round 19
// 303.030 us; speedup vs baseline: 1.0994x; 1.0023x over previous
//
#include <hip/hip_runtime.h>
#include <hip/hip_bf16.h>

// ---------------------------------------------------------------------------
// attention via: E = exp(QK^T/32) (bf16), inv[r] = 1/sum_k E[r,k] (per-wave
// partials), O = diag(inv)*E*V.
// r19 = r13 verbatim (best PASSING config, 302.9us, race-free).
// r18's failure exposed that the alternative gemm_pl template's tail reads
// race against other waves' global_load_lds (own-wave vmcnt certify only,
// reads BEFORE the barrier) — timing-masked in r11/r17, materialized under
// parity stagger. gemm8d is the correct pattern: counted WAITV BEFORE the
// closing barrier, new-buffer reads AFTER it (per-wave certify + barrier =
// global certify). Both GEMMs use it:
//   GEMM1: gemm8d<256,OUT=0,DEC=0>, grid 1024, supertile decode (FETCH 98MB).
//   GEMM2: gemm8d<128,OUT=1,DEC=1>, grid 256, stripe decode (~121us).
// 8 phases / 2 K-tiles, 2-tile-ahead staging into dead LDS regions, counted
// WAITV(6)/WAITV(4) at ph3/ph7 only (never 0 mid-loop), T2 both-sides XOR
// swizzle (0 conflicts), T5 setprio, de-pinned sync primitives.
// ws: [0,128MB)=E ; [128,144MB)=V^T ; [144,148MB)=partials ; then inv.
// d_out holds bf16 Q|K scratch until GEMM2 overwrites it.
// ---------------------------------------------------------------------------

typedef __bf16 bf16x8 __attribute__((ext_vector_type(8)));
typedef float f32x4 __attribute__((ext_vector_type(4)));
typedef const __attribute__((address_space(1))) unsigned int* as1p;
typedef __attribute__((address_space(3))) unsigned int* as3p;
typedef unsigned short u16;

__device__ __forceinline__ u16 f2bf(float x) {
  unsigned u = __float_as_uint(x);
  u += 0x7fffu + ((u >> 16) & 1u);
  return (u16)(u >> 16);
}
__device__ __forceinline__ float bf2f(u16 b) { return __uint_as_float(((unsigned)b) << 16); }
__device__ __forceinline__ unsigned pack2(float lo, float hi) {
  return (unsigned)f2bf(lo) | ((unsigned)f2bf(hi) << 16);
}

#define BARX()   __builtin_amdgcn_s_barrier()
#define WAITL()  asm volatile("s_waitcnt lgkmcnt(0)")
#define WAITV(n) asm volatile("s_waitcnt vmcnt(" #n ")")

// --------------------------- f32 -> bf16 convert ---------------------------
__global__ __launch_bounds__(256) void cvt_bf16(const float* __restrict__ in,
                                                unsigned short* __restrict__ out) {
  const size_t i = (size_t)blockIdx.x * 256 + threadIdx.x;
  const float4* p = (const float4*)in + i * 2;
  float4 a = p[0], b = p[1];
  uint4 o;
  o.x = pack2(a.x, a.y);
  o.y = pack2(a.z, a.w);
  o.z = pack2(b.x, b.y);
  o.w = pack2(b.z, b.w);
  ((uint4*)out)[i] = o;
}

// ------------- V [8192,1024] f32 -> V^T [1024,8192] bf16 -------------------
__global__ __launch_bounds__(256) void transpose_bf16(const float* __restrict__ V,
                                                      unsigned short* __restrict__ VT) {
  __shared__ float t[64][65];
  const int rb = blockIdx.x * 64;
  const int cb = blockIdx.y * 64;
  const int tid = threadIdx.x;
#pragma unroll
  for (int it = 0; it < 4; ++it) {
    int r = it * 16 + (tid >> 4);
    int c = (tid & 15) * 4;
    float4 x = *(const float4*)(V + (size_t)(rb + r) * 1024 + cb + c);
    t[r][c] = x.x; t[r][c + 1] = x.y; t[r][c + 2] = x.z; t[r][c + 3] = x.w;
  }
  __syncthreads();
  const int j = tid & 63;
  const int c0 = (tid >> 6) * 16;
#pragma unroll
  for (int i = 0; i < 16; ++i) {
    int c = c0 + i;
    VT[(size_t)(cb + c) * 8192 + rb + j] = f2bf(t[j][c]);
  }
}

// -------------- 8-phase NT GEMM, 2-tile-ahead staging, de-pinned -----------
// C[M,N](ldc) = A[M,K]*B[N,K]^T, BN=256. 512 threads, 8 waves (2M x 4N).
// DEC 0: grid 1024 = supertile 16bm x 8bn per XCD chunk   [GEMM1]
// DEC 1: grid 256  = 8bm x 4bn per XCD chunk (bn fastest) [GEMM2]
// OUTMODE 0: C=bf16 exp(acc*scale) + per-wave row partials.
// OUTMODE 1: C=f32 acc*inv[row].
template <int BM, int OUTMODE, int DEC>
__global__ __launch_bounds__(512, 2) void gemm8d(const u16* __restrict__ A,
                                                 const u16* __restrict__ B,
                                                 void* __restrict__ Cv,
                                                 const float* __restrict__ inv,
                                                 float* __restrict__ partials,
                                                 int K, int ldc, float scale) {
  constexpr int MF = BM / 32;       // per-wave m-frags (8 or 4)
  constexpr int MH = MF / 2;        // m-frags per half
  constexpr int ABUF = BM * 128;
  constexpr int BBUF = 32768;
  constexpr int BUFSZ = ABUF + BBUF;
  __shared__ __align__(1024) char smem[2 * BUFSZ];

  const int tid = threadIdx.x;
  const int lane = tid & 63, wave = tid >> 6;
  const int wr = wave >> 2, wc = wave & 3;
  const int lan15 = lane & 15, g = lane >> 4, l7 = lane & 7;

  // T1: bijective XCD swizzle (nwg % 8 == 0 at both call sites)
  const int nwg = gridDim.x;
  const int wg = (blockIdx.x & 7) * (nwg >> 3) + (blockIdx.x >> 3);
  int bm0, bn0;
  if constexpr (DEC == 0) {
    const int r = wg & 255;
    bm0 = (r >> 3) * 256;
    bn0 = (((wg >> 8) << 3) | (r & 7)) * 256;
  } else {
    // 256 wgs: XCD chunk of 32 = 8 bm x 4 bn, bn fastest -> the 4 blocks
    // sharing an S-row-stripe sit on ONE XCD (L2 serves 3 of 4 reads).
    const int chunk = wg >> 5;
    const int within = wg & 31;
    bm0 = (chunk * 8 + (within >> 2)) * BM;
    bn0 = (within & 3) * 256;
  }

  // staging: thread -> row (tid>>3), swizzled src col-block (tid&7)^(row&7)
  const int sr = tid >> 3;
  const int scb = ((tid & 7) ^ (sr & 7)) * 8;
  const u16* Ags = A + (size_t)(bm0 + sr) * K + scb;
  const u16* Bgs = B + (size_t)(bn0 + sr) * K + scb;

  // fragment-read swizzled 16B-slot offsets
  const int sa0 = ((0 + g) ^ l7) * 16;
  const int sa1 = ((4 + g) ^ l7) * 16;
  const int abase = (wr * (BM / 2) + lan15) * 128;
  const int bbase = ABUF + (wc * 64 + lan15) * 128;

  f32x4 acc[MF][4];
#pragma unroll
  for (int m = 0; m < MF; ++m)
#pragma unroll
    for (int n = 0; n < 4; ++n) acc[m][n] = f32x4{0.f, 0.f, 0.f, 0.f};

  const int nt = K >> 6;
  const int niter = nt >> 1;

  // stage units: 2 x global_load_lds each, explicit j-batches (64 rows each)
  auto IA = [&](int t, int ja, int jb) {
    char* bb = smem + (t & 1) * BUFSZ;
    const size_t ko = (size_t)t * 64;
    __builtin_amdgcn_global_load_lds((as1p)(Ags + (size_t)ja * 64 * K + ko),
                                     (as3p)(bb + ja * 8192 + tid * 16), 16, 0, 0);
    __builtin_amdgcn_global_load_lds((as1p)(Ags + (size_t)jb * 64 * K + ko),
                                     (as3p)(bb + jb * 8192 + tid * 16), 16, 0, 0);
  };
  auto IB = [&](int t, int j0) {  // batches j0, j0+1
    char* bb = smem + (t & 1) * BUFSZ + ABUF;
    const size_t ko = (size_t)t * 64;
    __builtin_amdgcn_global_load_lds((as1p)(Bgs + (size_t)j0 * 64 * K + ko),
                                     (as3p)(bb + j0 * 8192 + tid * 16), 16, 0, 0);
    __builtin_amdgcn_global_load_lds((as1p)(Bgs + (size_t)(j0 + 1) * 64 * K + ko),
                                     (as3p)(bb + (j0 + 1) * 8192 + tid * 16), 16, 0, 0);
  };
  auto IA_mh0 = [&](int t) { if constexpr (BM == 256) IA(t, 0, 2); };
  auto IA_mh1 = [&](int t) { if constexpr (BM == 256) IA(t, 1, 3); else IA(t, 0, 1); };

  bf16x8 a[MH][2], b[4][2];
  auto DS_A = [&](int bb, int mh) {
#pragma unroll
    for (int m = 0; m < MH; ++m) {
      a[m][0] = *(const bf16x8*)(smem + bb + abase + (mh * MH + m) * 2048 + sa0);
      a[m][1] = *(const bf16x8*)(smem + bb + abase + (mh * MH + m) * 2048 + sa1);
    }
  };
  auto DS_B = [&](int bb, int nh) {
#pragma unroll
    for (int n = 0; n < 2; ++n) {
      b[nh * 2 + n][0] = *(const bf16x8*)(smem + bb + bbase + (nh * 2 + n) * 2048 + sa0);
      b[nh * 2 + n][1] = *(const bf16x8*)(smem + bb + bbase + (nh * 2 + n) * 2048 + sa1);
    }
  };
  auto MMA = [&](int mh, int nh) {
    __builtin_amdgcn_s_setprio(1);
#pragma unroll
    for (int m = 0; m < MH; ++m)
#pragma unroll
      for (int n = 0; n < 2; ++n)
#pragma unroll
        for (int ks = 0; ks < 2; ++ks)
          acc[mh * MH + m][nh * 2 + n] = __builtin_amdgcn_mfma_f32_16x16x32_bf16(
              a[m][ks], b[nh * 2 + n][ks], acc[mh * MH + m][nh * 2 + n], 0, 0, 0);
    __builtin_amdgcn_s_setprio(0);
  };

  // ---- prologue: tile0 fully + tile1 {A-mh0, B}; force tile0 landed.
  if constexpr (BM == 256) {
    IA(0, 0, 2); IB(0, 0); IB(0, 2); IA(0, 1, 3);
    IA(1, 0, 2); IB(1, 0); IB(1, 2);
    WAITV(6);
  } else {
    IB(0, 0); IB(0, 2); IA(0, 0, 1);
    IB(1, 0); IB(1, 2);
    WAITV(4);
  }
  BARX();

  for (int i = 0; i < niter; ++i) {
    const int t0 = 2 * i;
    const bool more = (i + 1 < niter);

    // ---- ph0: buf0 (mh0,nh0); stage A-mh1(t0+1)
    DS_A(0, 0); DS_B(0, 0);
    IA_mh1(t0 + 1);
    BARX(); WAITL(); MMA(0, 0); BARX();

    // ---- ph1: buf0 (mh0,nh1); stage A-mh0(t0+2)
    DS_B(0, 1);
    if (more) IA_mh0(t0 + 2);
    BARX(); WAITL(); MMA(0, 1); BARX();

    // ---- ph2: buf0 (mh1,nh0); stage B-lo(t0+2)
    DS_A(0, 1);
    if (more) IB(t0 + 2, 0);
    BARX(); WAITL(); MMA(1, 0); BARX();

    // ---- ph3: buf0 (mh1,nh1); stage B-hi(t0+2); certify tile t0+1
    if (more) IB(t0 + 2, 2);
    BARX(); MMA(1, 1);
    if (more) { if constexpr (BM == 256) WAITV(6); else WAITV(4); } else { WAITV(0); }
    BARX();

    // ---- ph4: buf1 (mh0,nh0); stage A-mh1(t0+2)
    DS_A(BUFSZ, 0); DS_B(BUFSZ, 0);
    if (more) IA_mh1(t0 + 2);
    BARX(); WAITL(); MMA(0, 0); BARX();

    // ---- ph5: buf1 (mh0,nh1); stage A-mh0(t0+3)
    DS_B(BUFSZ, 1);
    if (more) IA_mh0(t0 + 3);
    BARX(); WAITL(); MMA(0, 1); BARX();

    // ---- ph6: buf1 (mh1,nh0); stage B-lo(t0+3)
    DS_A(BUFSZ, 1);
    if (more) IB(t0 + 3, 0);
    BARX(); WAITL(); MMA(1, 0); BARX();

    // ---- ph7: buf1 (mh1,nh1); stage B-hi(t0+3); certify tile t0+2
    if (more) IB(t0 + 3, 2);
    BARX(); MMA(1, 1);
    if (more) { if constexpr (BM == 256) WAITV(6); else WAITV(4); } else { WAITV(0); }
    BARX();
  }

  // ---- epilogue. C/D map: col = lane&15, row = (lane>>4)*4 + reg
  const int c0 = bn0 + wc * 64 + lan15;
  if constexpr (OUTMODE == 0) {
    u16* C = (u16*)Cv;
    const int cb4 = (bn0 >> 8) * 4 + wc;  // partial-column index (0..127)
#pragma unroll
    for (int m = 0; m < MF; ++m)
#pragma unroll
      for (int r = 0; r < 4; ++r) {
        const int row = bm0 + wr * (BM / 2) + m * 16 + g * 4 + r;
        float part = 0.f;
#pragma unroll
        for (int n = 0; n < 4; ++n) {
          float v = __expf(acc[m][n][r] * scale);
          C[(size_t)row * ldc + c0 + n * 16] = f2bf(v);
          part += v;
        }
        part += __shfl_xor(part, 1, 64);
        part += __shfl_xor(part, 2, 64);
        part += __shfl_xor(part, 4, 64);
        part += __shfl_xor(part, 8, 64);
        if (lan15 == 0) partials[(size_t)row * 128 + cb4] = part;
      }
  } else {
    float* C = (float*)Cv;
#pragma unroll
    for (int m = 0; m < MF; ++m)
#pragma unroll
      for (int r = 0; r < 4; ++r) {
        const int row = bm0 + wr * (BM / 2) + m * 16 + g * 4 + r;
        const float iv = inv ? inv[row] : 1.0f;
#pragma unroll
        for (int n = 0; n < 4; ++n)
          C[(size_t)row * ldc + c0 + n * 16] = acc[m][n][r] * iv;
      }
  }
}

// ---------------- inv[row] = 1 / sum_j partials[row][j] --------------------
__global__ __launch_bounds__(256) void rowinv(const float* __restrict__ partials,
                                              float* __restrict__ inv) {
  const int row = blockIdx.x * 256 + threadIdx.x;
  const float4* p = (const float4*)(partials + (size_t)row * 128);
  float s = 0.f;
#pragma unroll
  for (int j = 0; j < 32; ++j) {
    float4 v = p[j];
    s += (v.x + v.y) + (v.z + v.w);
  }
  inv[row] = 1.0f / s;
}

// --------------- fallback: normalize E rows in place (bf16) ----------------
__global__ __launch_bounds__(256) void normalize_inplace(u16* __restrict__ E) {
  __shared__ float red[4];
  u16* row = E + (size_t)blockIdx.x * 8192;
  const int tid = threadIdx.x;
  float f[32];
  float s = 0.f;
#pragma unroll
  for (int c = 0; c < 4; ++c) {
    uint4 v = *((const uint4*)row + c * 256 + tid);
    unsigned u[4] = {v.x, v.y, v.z, v.w};
#pragma unroll
    for (int q = 0; q < 4; ++q) {
      f[c * 8 + q * 2] = bf2f((u16)(u[q] & 0xffffu));
      f[c * 8 + q * 2 + 1] = bf2f((u16)(u[q] >> 16));
      s += f[c * 8 + q * 2] + f[c * 8 + q * 2 + 1];
    }
  }
#pragma unroll
  for (int off = 32; off; off >>= 1) s += __shfl_xor(s, off, 64);
  if ((tid & 63) == 0) red[tid >> 6] = s;
  __syncthreads();
  const float iv = 1.0f / ((red[0] + red[1]) + (red[2] + red[3]));
#pragma unroll
  for (int c = 0; c < 4; ++c) {
    uint4 o;
    o.x = pack2(f[c * 8 + 0] * iv, f[c * 8 + 1] * iv);
    o.y = pack2(f[c * 8 + 2] * iv, f[c * 8 + 3] * iv);
    o.z = pack2(f[c * 8 + 4] * iv, f[c * 8 + 5] * iv);
    o.w = pack2(f[c * 8 + 6] * iv, f[c * 8 + 7] * iv);
    *((uint4*)row + c * 256 + tid) = o;
  }
}

// ---------------------------------------------------------------------------
extern "C" void kernel_launch(void* const* d_in, const int* in_sizes, int n_in,
                              void* d_out, int out_size, void* d_ws, size_t ws_size,
                              hipStream_t stream) {
  const float* Q = (const float*)d_in[0];
  const float* K = (const float*)d_in[1];
  const float* V = (const float*)d_in[2];

  char* ws = (char*)d_ws;
  u16* S = (u16*)ws;                                              // 128 MB
  u16* VT = (u16*)(ws + (size_t)134217728);                       // 16 MB
  float* partials = (float*)(ws + (size_t)134217728 + 16777216);  // 4 MB
  float* inv = (float*)(ws + (size_t)134217728 + 16777216 + 4194304);
  const bool haveInv =
      ws_size >= (size_t)134217728 + 16777216 + 4194304 + 32768;

  u16* Qb = (u16*)d_out;   // bf16 Q scratch (16 MB)
  u16* Kb = Qb + 8388608;  // bf16 K scratch (16 MB)

  cvt_bf16<<<4096, 256, 0, stream>>>(Q, Qb);
  cvt_bf16<<<4096, 256, 0, stream>>>(K, Kb);
  transpose_bf16<<<dim3(128, 16), 256, 0, stream>>>(V, VT);

  // E = exp(Q K^T / 32)  [8192 x 8192] bf16 ; grid 1024 (supertile decode)
  gemm8d<256, 0, 0><<<1024, 512, 0, stream>>>(
      Qb, Kb, S, nullptr, haveInv ? partials : (float*)(ws + 134217728 + 16777216),
      1024, 8192, 1.0f / 32.0f);

  if (haveInv) {
    rowinv<<<32, 256, 0, stream>>>(partials, inv);
    // O = diag(inv) E V  [8192 x 1024] f32 ; grid 256 (stripe-sharing decode)
    gemm8d<128, 1, 1><<<256, 512, 0, stream>>>(
        S, VT, d_out, inv, nullptr, 8192, 1024, 1.0f);
  } else {
    normalize_inplace<<<8192, 256, 0, stream>>>(S);
    gemm8d<128, 1, 1><<<256, 512, 0, stream>>>(
        S, VT, d_out, nullptr, nullptr, 8192, 1024, 1.0f);
  }
}